// Round 12
// baseline (186.199 us; speedup 1.0000x reference)
//
#include <hip/hip_runtime.h>
#include <stdint.h>

#define BT 128
#define NN 1024
#define FF 128

typedef __attribute__((ext_vector_type(8))) short short8;
typedef __attribute__((ext_vector_type(4))) float float4v;
typedef __attribute__((ext_vector_type(4))) unsigned short ushort4v;

__device__ __forceinline__ unsigned short f2bf(float f) {
  uint32_t u = __builtin_bit_cast(uint32_t, f);
  u += 0x7FFFu + ((u >> 16) & 1u);   // RNE
  return (unsigned short)(u >> 16);
}

__device__ __forceinline__ void gload16(const void* g, void* l) {
  __builtin_amdgcn_global_load_lds(
      (const __attribute__((address_space(1))) uint32_t*)(g),
      (__attribute__((address_space(3))) uint32_t*)(l),
      16, 0, 0);
}

// ---- converts: S->Sbf (blk 0..63), W->Wk2 [k][o][f] (64..319), zbuf (320..327)
__global__ __launch_bounds__(256) void k_cvt_sw(const float* __restrict__ S,
                                                unsigned short* __restrict__ Sbf,
                                                const float* __restrict__ W,
                                                unsigned short* __restrict__ Wk2,
                                                unsigned short* __restrict__ zbuf) {
  int tid = threadIdx.x;
  int b = blockIdx.x;
  if (b < 64) {
#pragma unroll
    for (int i = 0; i < 16; ++i) {
      int g4 = b * 4096 + i * 256 + tid;
      float4v v = reinterpret_cast<const float4v*>(S)[g4];
      ushort4v h;
      h[0] = f2bf(v[0]); h[1] = f2bf(v[1]); h[2] = f2bf(v[2]); h[3] = f2bf(v[3]);
      reinterpret_cast<ushort4v*>(Sbf)[g4] = h;
    }
  } else if (b < 320) {
    int gid = (b - 64) * 256 + tid;
    int k = gid >> 14, o = (gid >> 7) & 127, f = gid & 127;
    Wk2[gid] = f2bf(W[(o * 128 + f) * 4 + k]);
  } else {
    ushort4v z = (ushort4v){0, 0, 0, 0};
#pragma unroll
    for (int i = 0; i < 16; ++i)
      reinterpret_cast<ushort4v*>(zbuf)[(b - 320) * 4096 + i * 256 + tid] = z;
  }
}

// X fp32 [bt][n][f] -> Xbf bf16 same layout (pure streaming)
__global__ __launch_bounds__(256) void k_cvt_x(const float* __restrict__ X,
                                               unsigned short* __restrict__ Xbf) {
  int base = blockIdx.x * 1024 + threadIdx.x;   // float4 units
#pragma unroll
  for (int i = 0; i < 4; ++i) {
    int g4 = base + i * 256;
    float4v v = reinterpret_cast<const float4v*>(X)[g4];
    ushort4v h;
    h[0] = f2bf(v[0]); h[1] = f2bf(v[1]); h[2] = f2bf(v[2]); h[3] = f2bf(v[3]);
    reinterpret_cast<ushort4v*>(Xbf)[g4] = h;
  }
}

// ---- k_proj: U3[bt][o][n] = sum_f W3[o][f] * Xbf[bt][n][f]  (K=128) --------
__global__ __launch_bounds__(256) void k_proj(const unsigned short* __restrict__ Wk2,
                                              const unsigned short* __restrict__ Xbf,
                                              unsigned short* __restrict__ U3) {
  __shared__ unsigned short lA[128 * 64];
  __shared__ unsigned short lB[128 * 64];
  int bt = blockIdx.x >> 3;
  int n0 = (blockIdx.x & 7) << 7;
  int tid = threadIdx.x;
  int wave = tid >> 6, lane = tid & 63;
  int wr = wave >> 1, wc = wave & 1;
  int lr = lane & 15, g = lane >> 4;

  const unsigned short* gA = Wk2 + 3 * (FF * FF);            // W3 [o][f], ld 128
  const unsigned short* gB = Xbf + (size_t)bt * (NN * FF) + (size_t)n0 * FF;  // [n][f]

  float4v acc[4][4];
#pragma unroll
  for (int a = 0; a < 4; ++a)
#pragma unroll
    for (int b = 0; b < 4; ++b) acc[a][b] = (float4v){0.f, 0.f, 0.f, 0.f};

  for (int kt = 0; kt < 2; ++kt) {
    int m0 = kt * 64;
#pragma unroll
    for (int i = 0; i < 4; ++i) {
      int id = i * 256 + tid;
      int row = id >> 3;
      int mc = (id & 7) << 3;
      int slot = (i * 256 + (tid & 192)) * 8;
      gload16(gA + (size_t)row * 128 + m0 + mc, &lA[slot]);
      gload16(gB + (size_t)row * 128 + m0 + mc, &lB[slot]);
    }
    __syncthreads();
#pragma unroll
    for (int kk = 0; kk < 2; ++kk) {
      short8 aF[4], bF[4];
#pragma unroll
      for (int mi = 0; mi < 4; ++mi)
        aF[mi] = *reinterpret_cast<const short8*>(
            &lA[(wr * 64 + mi * 16 + lr) * 64 + kk * 32 + g * 8]);
#pragma unroll
      for (int ni = 0; ni < 4; ++ni)
        bF[ni] = *reinterpret_cast<const short8*>(
            &lB[(wc * 64 + ni * 16 + lr) * 64 + kk * 32 + g * 8]);
#pragma unroll
      for (int mi = 0; mi < 4; ++mi)
#pragma unroll
        for (int ni = 0; ni < 4; ++ni)
          acc[mi][ni] = __builtin_amdgcn_mfma_f32_16x16x32_bf16(
              aF[mi], bF[ni], acc[mi][ni], 0, 0, 0);
    }
    __syncthreads();
  }

  unsigned short* Uo = U3 + (size_t)bt * (NN * FF);
#pragma unroll
  for (int mi = 0; mi < 4; ++mi) {
#pragma unroll
    for (int ni = 0; ni < 4; ++ni) {
      int o = wr * 64 + mi * 16 + g * 4;
      int n = n0 + wc * 64 + ni * 16 + lr;
#pragma unroll
      for (int j = 0; j < 4; ++j)
        Uo[(size_t)(o + j) * NN + n] = f2bf(acc[mi][ni][j]);
    }
  }
}

// ---- Horner chain step: Hout[t][o][n'] = sum_n Uin[t-1][o][n]*S[n'][n]
//                                        + sum_f Wg[o][f]*Xbf[t][n'][f]  (+bias)
// 2-phase/K-tile schedule: Phase A = {16 ds_reads (mh0,bF,cF), stage 6, 32 MFMA},
// Phase B = {8 ds_reads (mh1), stage 2, 32 MFMA; bF/cF stay live}.
// FIFO-derived waits: vmcnt(8)/vmcnt(8) steady state, vmcnt(2)/vmcnt(0) last.
template <bool FINAL>
__global__ __launch_bounds__(512, 2) void k_chain(
    const unsigned short* __restrict__ Uin,
    const unsigned short* __restrict__ Sbf,
    const unsigned short* __restrict__ Wg,     // Wk2 + kw*16384
    const unsigned short* __restrict__ Xbf,
    const unsigned short* __restrict__ zbuf,
    unsigned short* __restrict__ Hout,
    float* __restrict__ Yout,
    const float* __restrict__ bias) {
  extern __shared__ unsigned char lds[];   // 131072 B

  int bid = blockIdx.x;
  int logical = (bid & 7) * 32 + (bid >> 3);   // 256 = 8 x 32, bijective
  int cblk = logical >> 2;                     // 0..63  (bt pair)
  int nblk = logical & 3;                      // 0..3   (n' 256-block)

  int tid = threadIdx.x;
  int wave = tid >> 6, lane = tid & 63;
  int wave_m = wave >> 2, wave_n = wave & 3;
  int lr = lane & 15, g = lane >> 4;

  const int bt0 = cblk * 2;
  const bool t0z = ((bt0 & 31) == 0);
  const unsigned short* A0 = t0z ? zbuf : (Uin + (size_t)(bt0 - 1) * (NN * FF));
  const unsigned short* A1 = Uin + (size_t)bt0 * (NN * FF);

  // ---- staging pointers: sets 0=SA0, 1=SB0, 2=SB1, 3=SA1; 2 instr each.
  const unsigned short* pS[4][2];
  unsigned dstO[4][2];
#pragma unroll
  for (int j = 0; j < 2; ++j) {
    int sr0 = wave * 16 + j * 8;
    int rbA = (sr0 & 63) + ((sr0 >> 6) << 7);
    int rbB = (sr0 & 31) + ((sr0 >> 5) << 6);
    int seg = lane & 7;
    int rA0 = rbA + (lane >> 3), rA1 = rA0 + 64;
    int rB0 = rbB + (lane >> 3), rB1 = rB0 + 32;
    pS[0][j] = (rA0 < 128 ? A0 + (size_t)rA0 * NN : A1 + (size_t)(rA0 - 128) * NN)
               + ((seg ^ (rA0 & 7)) << 3);
    pS[3][j] = (rA1 < 128 ? A0 + (size_t)rA1 * NN : A1 + (size_t)(rA1 - 128) * NN)
               + ((seg ^ (rA1 & 7)) << 3);
    pS[1][j] = Sbf + (size_t)(nblk * 256 + rB0) * NN + ((seg ^ (rB0 & 7)) << 3);
    pS[2][j] = Sbf + (size_t)(nblk * 256 + rB1) * NN + ((seg ^ (rB1 & 7)) << 3);
    dstO[0][j] = (unsigned)rbA * 128u;
    dstO[3][j] = (unsigned)(rbA + 64) * 128u;
    dstO[1][j] = 32768u + (unsigned)rbB * 128u;
    dstO[2][j] = 32768u + (unsigned)(rbB + 32) * 128u;
  }

  // ---- ds_read constants
  const unsigned xm = (unsigned)((lr & 7) << 4);
  const unsigned xo0 = ((unsigned)(g * 16)) ^ xm;
  const unsigned xo1 = ((unsigned)(64 + g * 16)) ^ xm;
  const unsigned aRB = (unsigned)((wave_m * 128 + lr) * 128);
  const unsigned bRB = 32768u + (unsigned)((wave_n * 64 + lr) * 128);

#define RD(OFF) (*reinterpret_cast<const short8*>(lds + (OFF)))

  float4v acc[8][4];
#pragma unroll
  for (int a = 0; a < 8; ++a)
#pragma unroll
    for (int b = 0; b < 4; ++b) acc[a][b] = (float4v){0.f, 0.f, 0.f, 0.f};

  short8 aF[4][2], nB[4][2];

  // ---- prologue: stage kt0 into buf0
#pragma unroll
  for (int s = 0; s < 4; ++s)
#pragma unroll
    for (int j = 0; j < 2; ++j) gload16(pS[s][j], lds + dstO[s][j]);
  asm volatile("s_waitcnt vmcnt(0)" ::: "memory");
  __builtin_amdgcn_s_barrier();

  for (int kt = 0; kt < 16; ++kt) {
    const unsigned bo = (unsigned)(kt & 1) << 16;
    const unsigned nbo = bo ^ 65536u;
    const unsigned ko = (unsigned)(kt + 1) * 64u;
    const bool st = (kt < 15);

    // ===== Phase A: 16 reads (aF mh0; nB = bF,cF); stage SA0',SB0',SB1' ====
#pragma unroll
    for (int mf = 0; mf < 4; ++mf) {
      aF[mf][0] = RD(bo + aRB + (unsigned)mf * 2048u + xo0);
      aF[mf][1] = RD(bo + aRB + (unsigned)mf * 2048u + xo1);
    }
#pragma unroll
    for (int nf = 0; nf < 4; ++nf) {          // nf 0,1 = SB0 rows; 2,3 = SB1
      nB[nf][0] = RD(bo + bRB + (unsigned)nf * 2048u + xo0);
      nB[nf][1] = RD(bo + bRB + (unsigned)nf * 2048u + xo1);
    }
    if (st) {
      gload16(pS[0][0] + ko, lds + nbo + dstO[0][0]);
      gload16(pS[0][1] + ko, lds + nbo + dstO[0][1]);
      gload16(pS[1][0] + ko, lds + nbo + dstO[1][0]);
      gload16(pS[1][1] + ko, lds + nbo + dstO[1][1]);
      gload16(pS[2][0] + ko, lds + nbo + dstO[2][0]);
      gload16(pS[2][1] + ko, lds + nbo + dstO[2][1]);
      asm volatile("s_waitcnt lgkmcnt(8) vmcnt(8)" ::: "memory");
    } else {
      asm volatile("s_waitcnt lgkmcnt(8) vmcnt(2)" ::: "memory");
    }
    __builtin_amdgcn_s_barrier();
    asm volatile("s_waitcnt lgkmcnt(0)" ::: "memory");
    __builtin_amdgcn_sched_barrier(0);
    __builtin_amdgcn_s_setprio(1);
#pragma unroll
    for (int mf = 0; mf < 4; ++mf)
#pragma unroll
      for (int nf = 0; nf < 4; ++nf) {
        acc[mf][nf] = __builtin_amdgcn_mfma_f32_16x16x32_bf16(aF[mf][0], nB[nf][0], acc[mf][nf], 0, 0, 0);
        acc[mf][nf] = __builtin_amdgcn_mfma_f32_16x16x32_bf16(aF[mf][1], nB[nf][1], acc[mf][nf], 0, 0, 0);
      }
    __builtin_amdgcn_s_setprio(0);
    __builtin_amdgcn_sched_barrier(0);
    __builtin_amdgcn_s_barrier();
    __builtin_amdgcn_sched_barrier(0);

    // ===== Phase B: 8 reads (aF mh1); stage SA1'; nB stays live ============
#pragma unroll
    for (int mf = 0; mf < 4; ++mf) {
      aF[mf][0] = RD(bo + aRB + 8192u + (unsigned)mf * 2048u + xo0);
      aF[mf][1] = RD(bo + aRB + 8192u + (unsigned)mf * 2048u + xo1);
    }
    if (st) {
      gload16(pS[3][0] + ko, lds + nbo + dstO[3][0]);
      gload16(pS[3][1] + ko, lds + nbo + dstO[3][1]);
      asm volatile("s_waitcnt lgkmcnt(4) vmcnt(8)" ::: "memory");
    } else {
      asm volatile("s_waitcnt lgkmcnt(4) vmcnt(0)" ::: "memory");
    }
    __builtin_amdgcn_s_barrier();
    asm volatile("s_waitcnt lgkmcnt(0)" ::: "memory");
    __builtin_amdgcn_sched_barrier(0);
    __builtin_amdgcn_s_setprio(1);
#pragma unroll
    for (int mf = 0; mf < 4; ++mf)
#pragma unroll
      for (int nf = 0; nf < 4; ++nf) {
        acc[4 + mf][nf] = __builtin_amdgcn_mfma_f32_16x16x32_bf16(aF[mf][0], nB[nf][0], acc[4 + mf][nf], 0, 0, 0);
        acc[4 + mf][nf] = __builtin_amdgcn_mfma_f32_16x16x32_bf16(aF[mf][1], nB[nf][1], acc[4 + mf][nf], 0, 0, 0);
      }
    __builtin_amdgcn_s_setprio(0);
    __builtin_amdgcn_sched_barrier(0);
    __builtin_amdgcn_s_barrier();
    __builtin_amdgcn_sched_barrier(0);
  }
#undef RD

  // ---- W-part: acc[mf][nf] += Wg[o][f] (x) Xbf[bt][n'][f], K=128 ----------
  int bt = bt0 + wave_m;
  const unsigned short* Xb = Xbf + (size_t)bt * (NN * FF);
  const int nbase = nblk * 256 + wave_n * 64;
#pragma unroll
  for (int kk = 0; kk < 4; ++kk) {
    int fc = kk * 32 + g * 8;
    short8 aW[8], bW[4];
#pragma unroll
    for (int mf = 0; mf < 8; ++mf)
      aW[mf] = *reinterpret_cast<const short8*>(Wg + (size_t)(mf * 16 + lr) * FF + fc);
#pragma unroll
    for (int nf = 0; nf < 4; ++nf)
      bW[nf] = *reinterpret_cast<const short8*>(Xb + (size_t)(nbase + nf * 16 + lr) * FF + fc);
#pragma unroll
    for (int mf = 0; mf < 8; ++mf)
#pragma unroll
      for (int nf = 0; nf < 4; ++nf)
        acc[mf][nf] = __builtin_amdgcn_mfma_f32_16x16x32_bf16(aW[mf], bW[nf], acc[mf][nf], 0, 0, 0);
  }

  // ---- epilogue: D row = o (A-row), D col = n' (B-row) --------------------
  if constexpr (FINAL) {
    float* Yp = Yout + (size_t)bt * (NN * FF);
#pragma unroll
    for (int i = 0; i < 8; ++i) {
      int o0 = i * 16 + g * 4;
      float4v bv = *reinterpret_cast<const float4v*>(bias + o0);
#pragma unroll
      for (int j2 = 0; j2 < 4; ++j2) {
        int n = nbase + j2 * 16 + lr;
        float4v r = acc[i][j2] + bv;
        *reinterpret_cast<float4v*>(Yp + (size_t)n * FF + o0) = r;
      }
    }
  } else {
    unsigned short* Hp = Hout + (size_t)bt * (NN * FF);
#pragma unroll
    for (int i = 0; i < 8; ++i) {
      int o0 = i * 16 + g * 4;
#pragma unroll
      for (int j2 = 0; j2 < 4; ++j2) {
        int n = nbase + j2 * 16 + lr;
#pragma unroll
        for (int j = 0; j < 4; ++j)
          Hp[(size_t)(o0 + j) * NN + n] = f2bf(acc[i][j2][j]);
      }
    }
  }
}

// ---- launch ----------------------------------------------------------------

extern "C" void kernel_launch(void* const* d_in, const int* in_sizes, int n_in,
                              void* d_out, int out_size, void* d_ws, size_t ws_size,
                              hipStream_t stream) {
  const float* X = (const float*)d_in[0];
  const float* S = (const float*)d_in[1];
  const float* W = (const float*)d_in[2];
  const float* bvec = (const float*)d_in[3];
  float* Y = (float*)d_out;

  char* ws = (char*)d_ws;
  const size_t ZB = (size_t)BT * NN * FF * sizeof(unsigned short);  // 32 MiB
  unsigned short* Xbf = (unsigned short*)(ws + 0 * ZB);
  unsigned short* U3  = (unsigned short*)(ws + 1 * ZB);
  unsigned short* H2  = (unsigned short*)(ws + 2 * ZB);
  unsigned short* H1  = (unsigned short*)(ws + 3 * ZB);
  unsigned short* Sbf = (unsigned short*)(ws + 4 * ZB);                    // 2 MiB
  unsigned short* Wk2 = (unsigned short*)(ws + 4 * ZB + (size_t)2097152);  // 128 KiB
  unsigned short* zbf = (unsigned short*)(ws + 4 * ZB + (size_t)2097152 + 131072);  // 256 KiB

  k_cvt_sw<<<dim3(328), dim3(256), 0, stream>>>(S, Sbf, W, Wk2, zbf);
  k_cvt_x<<<dim3(4096), dim3(256), 0, stream>>>(X, Xbf);
  k_proj<<<dim3(1024), dim3(256), 0, stream>>>(Wk2, Xbf, U3);

  hipError_t e0 = hipFuncSetAttribute((const void*)k_chain<false>,
                      hipFuncAttributeMaxDynamicSharedMemorySize, 131072);
  hipError_t e1 = hipFuncSetAttribute((const void*)k_chain<true>,
                      hipFuncAttributeMaxDynamicSharedMemorySize, 131072);
  (void)e0; (void)e1;

  // H2 = S*U3[t-1] + X*W2^T
  k_chain<false><<<dim3(256), dim3(512), 131072, stream>>>(
      U3, Sbf, Wk2 + 2 * (FF * FF), Xbf, zbf, H2, nullptr, nullptr);
  // H1 = S*H2[t-1] + X*W1^T
  k_chain<false><<<dim3(256), dim3(512), 131072, stream>>>(
      H2, Sbf, Wk2 + 1 * (FF * FF), Xbf, zbf, H1, nullptr, nullptr);
  // Y = S*H1[t-1] + X*W0^T + b
  k_chain<true><<<dim3(256), dim3(512), 131072, stream>>>(
      H1, Sbf, Wk2, Xbf, zbf, nullptr, Y, bvec);
}

// Round 13
// 179.613 us; speedup vs baseline: 1.0367x; 1.0367x over previous
//
#include <hip/hip_runtime.h>
#include <stdint.h>

#define BT 128
#define NN 1024
#define FF 128

typedef __attribute__((ext_vector_type(8))) short short8;
typedef __attribute__((ext_vector_type(4))) float float4v;
typedef __attribute__((ext_vector_type(4))) unsigned short ushort4v;

__device__ __forceinline__ unsigned short f2bf(float f) {
  uint32_t u = __builtin_bit_cast(uint32_t, f);
  u += 0x7FFFu + ((u >> 16) & 1u);   // RNE
  return (unsigned short)(u >> 16);
}

__device__ __forceinline__ void gload16(const void* g, void* l) {
  __builtin_amdgcn_global_load_lds(
      (const __attribute__((address_space(1))) uint32_t*)(g),
      (__attribute__((address_space(3))) uint32_t*)(l),
      16, 0, 0);
}

// ---- converts: S->Sbf (blk 0..63), W->Wk2 [k][o][f] (64..319), zbuf (320..327)
__global__ __launch_bounds__(256) void k_cvt_sw(const float* __restrict__ S,
                                                unsigned short* __restrict__ Sbf,
                                                const float* __restrict__ W,
                                                unsigned short* __restrict__ Wk2,
                                                unsigned short* __restrict__ zbuf) {
  int tid = threadIdx.x;
  int b = blockIdx.x;
  if (b < 64) {
#pragma unroll
    for (int i = 0; i < 16; ++i) {
      int g4 = b * 4096 + i * 256 + tid;
      float4v v = reinterpret_cast<const float4v*>(S)[g4];
      ushort4v h;
      h[0] = f2bf(v[0]); h[1] = f2bf(v[1]); h[2] = f2bf(v[2]); h[3] = f2bf(v[3]);
      reinterpret_cast<ushort4v*>(Sbf)[g4] = h;
    }
  } else if (b < 320) {
    int gid = (b - 64) * 256 + tid;
    int k = gid >> 14, o = (gid >> 7) & 127, f = gid & 127;
    Wk2[gid] = f2bf(W[(o * 128 + f) * 4 + k]);
  } else {
    ushort4v z = (ushort4v){0, 0, 0, 0};
#pragma unroll
    for (int i = 0; i < 16; ++i)
      reinterpret_cast<ushort4v*>(zbuf)[(b - 320) * 4096 + i * 256 + tid] = z;
  }
}

// X fp32 [bt][n][f] -> Xbf bf16 same layout (pure streaming)
__global__ __launch_bounds__(256) void k_cvt_x(const float* __restrict__ X,
                                               unsigned short* __restrict__ Xbf) {
  int base = blockIdx.x * 1024 + threadIdx.x;   // float4 units
#pragma unroll
  for (int i = 0; i < 4; ++i) {
    int g4 = base + i * 256;
    float4v v = reinterpret_cast<const float4v*>(X)[g4];
    ushort4v h;
    h[0] = f2bf(v[0]); h[1] = f2bf(v[1]); h[2] = f2bf(v[2]); h[3] = f2bf(v[3]);
    reinterpret_cast<ushort4v*>(Xbf)[g4] = h;
  }
}

// ---- k_proj: U3[bt][o][n] = sum_f W3[o][f] * Xbf[bt][n][f]  (K=128) --------
__global__ __launch_bounds__(256) void k_proj(const unsigned short* __restrict__ Wk2,
                                              const unsigned short* __restrict__ Xbf,
                                              unsigned short* __restrict__ U3) {
  __shared__ unsigned short lA[128 * 64];
  __shared__ unsigned short lB[128 * 64];
  int bt = blockIdx.x >> 3;
  int n0 = (blockIdx.x & 7) << 7;
  int tid = threadIdx.x;
  int wave = tid >> 6, lane = tid & 63;
  int wr = wave >> 1, wc = wave & 1;
  int lr = lane & 15, g = lane >> 4;

  const unsigned short* gA = Wk2 + 3 * (FF * FF);            // W3 [o][f], ld 128
  const unsigned short* gB = Xbf + (size_t)bt * (NN * FF) + (size_t)n0 * FF;  // [n][f]

  float4v acc[4][4];
#pragma unroll
  for (int a = 0; a < 4; ++a)
#pragma unroll
    for (int b = 0; b < 4; ++b) acc[a][b] = (float4v){0.f, 0.f, 0.f, 0.f};

  for (int kt = 0; kt < 2; ++kt) {
    int m0 = kt * 64;
#pragma unroll
    for (int i = 0; i < 4; ++i) {
      int id = i * 256 + tid;
      int row = id >> 3;
      int mc = (id & 7) << 3;
      int slot = (i * 256 + (tid & 192)) * 8;
      gload16(gA + (size_t)row * 128 + m0 + mc, &lA[slot]);
      gload16(gB + (size_t)row * 128 + m0 + mc, &lB[slot]);
    }
    __syncthreads();
#pragma unroll
    for (int kk = 0; kk < 2; ++kk) {
      short8 aF[4], bF[4];
#pragma unroll
      for (int mi = 0; mi < 4; ++mi)
        aF[mi] = *reinterpret_cast<const short8*>(
            &lA[(wr * 64 + mi * 16 + lr) * 64 + kk * 32 + g * 8]);
#pragma unroll
      for (int ni = 0; ni < 4; ++ni)
        bF[ni] = *reinterpret_cast<const short8*>(
            &lB[(wc * 64 + ni * 16 + lr) * 64 + kk * 32 + g * 8]);
#pragma unroll
      for (int mi = 0; mi < 4; ++mi)
#pragma unroll
        for (int ni = 0; ni < 4; ++ni)
          acc[mi][ni] = __builtin_amdgcn_mfma_f32_16x16x32_bf16(
              aF[mi], bF[ni], acc[mi][ni], 0, 0, 0);
    }
    __syncthreads();
  }

  unsigned short* Uo = U3 + (size_t)bt * (NN * FF);
#pragma unroll
  for (int mi = 0; mi < 4; ++mi) {
#pragma unroll
    for (int ni = 0; ni < 4; ++ni) {
      int o = wr * 64 + mi * 16 + g * 4;
      int n = n0 + wc * 64 + ni * 16 + lr;
#pragma unroll
      for (int j = 0; j < 4; ++j)
        Uo[(size_t)(o + j) * NN + n] = f2bf(acc[mi][ni][j]);
    }
  }
}

// ---- Horner chain step: Hout[t][o][n'] = sum_n Uin[t-1][o][n]*S[n'][n]
//                                        + sum_f Wg[o][f]*Xbf[t][n'][f]  (+bias)
// 4 balanced phases/K-tile (mh,kk quadrants): 8/8/4/4 ds_reads x 16 MFMA each.
// B-frags (both kk halves) stay live across the K-tile. Stage sets
// SA0@P0, SB0@P1, SB1@P2, SA1@P3; FIFO waits vmcnt(4)/P0, (4)/P1, -, (2)/P3.
template <bool FINAL>
__global__ __launch_bounds__(512, 2) void k_chain(
    const unsigned short* __restrict__ Uin,
    const unsigned short* __restrict__ Sbf,
    const unsigned short* __restrict__ Wg,     // Wk2 + kw*16384
    const unsigned short* __restrict__ Xbf,
    const unsigned short* __restrict__ zbuf,
    unsigned short* __restrict__ Hout,
    float* __restrict__ Yout,
    const float* __restrict__ bias) {
  extern __shared__ unsigned char lds[];   // 131072 B

  int bid = blockIdx.x;
  int logical = (bid & 7) * 32 + (bid >> 3);   // 256 = 8 x 32, bijective
  int cblk = logical >> 2;                     // 0..63  (bt pair)
  int nblk = logical & 3;                      // 0..3   (n' 256-block)

  int tid = threadIdx.x;
  int wave = tid >> 6, lane = tid & 63;
  int wave_m = wave >> 2, wave_n = wave & 3;
  int lr = lane & 15, g = lane >> 4;

  const int bt0 = cblk * 2;
  const bool t0z = ((bt0 & 31) == 0);
  const unsigned short* A0 = t0z ? zbuf : (Uin + (size_t)(bt0 - 1) * (NN * FF));
  const unsigned short* A1 = Uin + (size_t)bt0 * (NN * FF);

  // ---- staging pointers: sets 0=SA0, 1=SB0, 2=SB1, 3=SA1; 2 instr each.
  const unsigned short* pS[4][2];
  unsigned dstO[4][2];
#pragma unroll
  for (int j = 0; j < 2; ++j) {
    int sr0 = wave * 16 + j * 8;
    int rbA = (sr0 & 63) + ((sr0 >> 6) << 7);
    int rbB = (sr0 & 31) + ((sr0 >> 5) << 6);
    int seg = lane & 7;
    int rA0 = rbA + (lane >> 3), rA1 = rA0 + 64;
    int rB0 = rbB + (lane >> 3), rB1 = rB0 + 32;
    pS[0][j] = (rA0 < 128 ? A0 + (size_t)rA0 * NN : A1 + (size_t)(rA0 - 128) * NN)
               + ((seg ^ (rA0 & 7)) << 3);
    pS[3][j] = (rA1 < 128 ? A0 + (size_t)rA1 * NN : A1 + (size_t)(rA1 - 128) * NN)
               + ((seg ^ (rA1 & 7)) << 3);
    pS[1][j] = Sbf + (size_t)(nblk * 256 + rB0) * NN + ((seg ^ (rB0 & 7)) << 3);
    pS[2][j] = Sbf + (size_t)(nblk * 256 + rB1) * NN + ((seg ^ (rB1 & 7)) << 3);
    dstO[0][j] = (unsigned)rbA * 128u;
    dstO[3][j] = (unsigned)(rbA + 64) * 128u;
    dstO[1][j] = 32768u + (unsigned)rbB * 128u;
    dstO[2][j] = 32768u + (unsigned)(rbB + 32) * 128u;
  }

  // ---- ds_read constants
  const unsigned xm = (unsigned)((lr & 7) << 4);
  const unsigned xo0 = ((unsigned)(g * 16)) ^ xm;
  const unsigned xo1 = ((unsigned)(64 + g * 16)) ^ xm;
  const unsigned aRB = (unsigned)((wave_m * 128 + lr) * 128);
  const unsigned bRB = 32768u + (unsigned)((wave_n * 64 + lr) * 128);

#define RD(OFF) (*reinterpret_cast<const short8*>(lds + (OFF)))

  float4v acc[8][4];
#pragma unroll
  for (int a = 0; a < 8; ++a)
#pragma unroll
    for (int b = 0; b < 4; ++b) acc[a][b] = (float4v){0.f, 0.f, 0.f, 0.f};

  short8 aX[4], aY[4], nB0[4], nB1[4];

  // ---- prologue: stage kt0 into buf0
#pragma unroll
  for (int s = 0; s < 4; ++s)
#pragma unroll
    for (int j = 0; j < 2; ++j) gload16(pS[s][j], lds + dstO[s][j]);
  asm volatile("s_waitcnt vmcnt(0)" ::: "memory");
  __builtin_amdgcn_s_barrier();

  for (int kt = 0; kt < 16; ++kt) {
    const unsigned bo = (unsigned)(kt & 1) << 16;
    const unsigned nbo = bo ^ 65536u;
    const unsigned ko = (unsigned)(kt + 1) * 64u;
    const bool st = (kt < 15);

    // ===== P0 (mh0,kk0): 8 reads; stage SA0' =====
#pragma unroll
    for (int mf = 0; mf < 4; ++mf) aX[mf] = RD(bo + aRB + (unsigned)mf * 2048u + xo0);
#pragma unroll
    for (int nf = 0; nf < 4; ++nf) nB0[nf] = RD(bo + bRB + (unsigned)nf * 2048u + xo0);
    if (st) {
      gload16(pS[0][0] + ko, lds + nbo + dstO[0][0]);
      gload16(pS[0][1] + ko, lds + nbo + dstO[0][1]);
      asm volatile("s_waitcnt vmcnt(4)" ::: "memory");
    }
    __builtin_amdgcn_s_barrier();
    asm volatile("s_waitcnt lgkmcnt(0)" ::: "memory");
    __builtin_amdgcn_sched_barrier(0);
    __builtin_amdgcn_s_setprio(1);
#pragma unroll
    for (int mf = 0; mf < 4; ++mf)
#pragma unroll
      for (int nf = 0; nf < 4; ++nf)
        acc[mf][nf] = __builtin_amdgcn_mfma_f32_16x16x32_bf16(aX[mf], nB0[nf], acc[mf][nf], 0, 0, 0);
    __builtin_amdgcn_s_setprio(0);
    __builtin_amdgcn_sched_barrier(0);
    __builtin_amdgcn_s_barrier();
    __builtin_amdgcn_sched_barrier(0);

    // ===== P1 (mh0,kk1): 8 reads; stage SB0' =====
#pragma unroll
    for (int mf = 0; mf < 4; ++mf) aY[mf] = RD(bo + aRB + (unsigned)mf * 2048u + xo1);
#pragma unroll
    for (int nf = 0; nf < 4; ++nf) nB1[nf] = RD(bo + bRB + (unsigned)nf * 2048u + xo1);
    if (st) {
      gload16(pS[1][0] + ko, lds + nbo + dstO[1][0]);
      gload16(pS[1][1] + ko, lds + nbo + dstO[1][1]);
      asm volatile("s_waitcnt vmcnt(4)" ::: "memory");   // retire SA1(cur)
    } else {
      asm volatile("s_waitcnt vmcnt(0)" ::: "memory");
    }
    __builtin_amdgcn_s_barrier();
    asm volatile("s_waitcnt lgkmcnt(0)" ::: "memory");
    __builtin_amdgcn_sched_barrier(0);
    __builtin_amdgcn_s_setprio(1);
#pragma unroll
    for (int mf = 0; mf < 4; ++mf)
#pragma unroll
      for (int nf = 0; nf < 4; ++nf)
        acc[mf][nf] = __builtin_amdgcn_mfma_f32_16x16x32_bf16(aY[mf], nB1[nf], acc[mf][nf], 0, 0, 0);
    __builtin_amdgcn_s_setprio(0);
    __builtin_amdgcn_sched_barrier(0);
    __builtin_amdgcn_s_barrier();
    __builtin_amdgcn_sched_barrier(0);

    // ===== P2 (mh1,kk0): 4 reads; stage SB1'; no vm wait =====
#pragma unroll
    for (int mf = 0; mf < 4; ++mf) aX[mf] = RD(bo + aRB + 8192u + (unsigned)mf * 2048u + xo0);
    if (st) {
      gload16(pS[2][0] + ko, lds + nbo + dstO[2][0]);
      gload16(pS[2][1] + ko, lds + nbo + dstO[2][1]);
    }
    __builtin_amdgcn_s_barrier();
    asm volatile("s_waitcnt lgkmcnt(0)" ::: "memory");
    __builtin_amdgcn_sched_barrier(0);
    __builtin_amdgcn_s_setprio(1);
#pragma unroll
    for (int mf = 0; mf < 4; ++mf)
#pragma unroll
      for (int nf = 0; nf < 4; ++nf)
        acc[4 + mf][nf] = __builtin_amdgcn_mfma_f32_16x16x32_bf16(aX[mf], nB0[nf], acc[4 + mf][nf], 0, 0, 0);
    __builtin_amdgcn_s_setprio(0);
    __builtin_amdgcn_sched_barrier(0);
    __builtin_amdgcn_s_barrier();
    __builtin_amdgcn_sched_barrier(0);

    // ===== P3 (mh1,kk1): 4 reads; stage SA1'; vmcnt(2) =====
#pragma unroll
    for (int mf = 0; mf < 4; ++mf) aY[mf] = RD(bo + aRB + 8192u + (unsigned)mf * 2048u + xo1);
    if (st) {
      gload16(pS[3][0] + ko, lds + nbo + dstO[3][0]);
      gload16(pS[3][1] + ko, lds + nbo + dstO[3][1]);
      asm volatile("s_waitcnt vmcnt(2)" ::: "memory");   // retire SA0',SB0',SB1'
    }
    __builtin_amdgcn_s_barrier();
    asm volatile("s_waitcnt lgkmcnt(0)" ::: "memory");
    __builtin_amdgcn_sched_barrier(0);
    __builtin_amdgcn_s_setprio(1);
#pragma unroll
    for (int mf = 0; mf < 4; ++mf)
#pragma unroll
      for (int nf = 0; nf < 4; ++nf)
        acc[4 + mf][nf] = __builtin_amdgcn_mfma_f32_16x16x32_bf16(aY[mf], nB1[nf], acc[4 + mf][nf], 0, 0, 0);
    __builtin_amdgcn_s_setprio(0);
    __builtin_amdgcn_sched_barrier(0);
    __builtin_amdgcn_s_barrier();
    __builtin_amdgcn_sched_barrier(0);
  }
#undef RD

  // ---- W-part: acc[mf][nf] += Wg[o][f] (x) Xbf[bt][n'][f], K=128 ----------
  int bt = bt0 + wave_m;
  const unsigned short* Xb = Xbf + (size_t)bt * (NN * FF);
  const int nbase = nblk * 256 + wave_n * 64;
#pragma unroll 1
  for (int kk = 0; kk < 4; ++kk) {
    int fc = kk * 32 + g * 8;
    short8 aW[8], bW[4];
#pragma unroll
    for (int mf = 0; mf < 8; ++mf)
      aW[mf] = *reinterpret_cast<const short8*>(Wg + (size_t)(mf * 16 + lr) * FF + fc);
#pragma unroll
    for (int nf = 0; nf < 4; ++nf)
      bW[nf] = *reinterpret_cast<const short8*>(Xb + (size_t)(nbase + nf * 16 + lr) * FF + fc);
#pragma unroll
    for (int mf = 0; mf < 8; ++mf)
#pragma unroll
      for (int nf = 0; nf < 4; ++nf)
        acc[mf][nf] = __builtin_amdgcn_mfma_f32_16x16x32_bf16(aW[mf], bW[nf], acc[mf][nf], 0, 0, 0);
  }

  // ---- epilogue: D row = o (A-row), D col = n' (B-row) --------------------
  if constexpr (FINAL) {
    float* Yp = Yout + (size_t)bt * (NN * FF);
#pragma unroll
    for (int i = 0; i < 8; ++i) {
      int o0 = i * 16 + g * 4;
      float4v bv = *reinterpret_cast<const float4v*>(bias + o0);
#pragma unroll
      for (int j2 = 0; j2 < 4; ++j2) {
        int n = nbase + j2 * 16 + lr;
        float4v r = acc[i][j2] + bv;
        *reinterpret_cast<float4v*>(Yp + (size_t)n * FF + o0) = r;
      }
    }
  } else {
    unsigned short* Hp = Hout + (size_t)bt * (NN * FF);
#pragma unroll
    for (int i = 0; i < 8; ++i) {
      int o0 = i * 16 + g * 4;
#pragma unroll
      for (int j2 = 0; j2 < 4; ++j2) {
        int n = nbase + j2 * 16 + lr;
#pragma unroll
        for (int j = 0; j < 4; ++j)
          Hp[(size_t)(o0 + j) * NN + n] = f2bf(acc[i][j2][j]);
      }
    }
  }
}

// ---- launch ----------------------------------------------------------------

extern "C" void kernel_launch(void* const* d_in, const int* in_sizes, int n_in,
                              void* d_out, int out_size, void* d_ws, size_t ws_size,
                              hipStream_t stream) {
  const float* X = (const float*)d_in[0];
  const float* S = (const float*)d_in[1];
  const float* W = (const float*)d_in[2];
  const float* bvec = (const float*)d_in[3];
  float* Y = (float*)d_out;

  char* ws = (char*)d_ws;
  const size_t ZB = (size_t)BT * NN * FF * sizeof(unsigned short);  // 32 MiB
  unsigned short* Xbf = (unsigned short*)(ws + 0 * ZB);
  unsigned short* U3  = (unsigned short*)(ws + 1 * ZB);
  unsigned short* H2  = (unsigned short*)(ws + 2 * ZB);
  unsigned short* H1  = (unsigned short*)(ws + 3 * ZB);
  unsigned short* Sbf = (unsigned short*)(ws + 4 * ZB);                    // 2 MiB
  unsigned short* Wk2 = (unsigned short*)(ws + 4 * ZB + (size_t)2097152);  // 128 KiB
  unsigned short* zbf = (unsigned short*)(ws + 4 * ZB + (size_t)2097152 + 131072);  // 256 KiB

  k_cvt_sw<<<dim3(328), dim3(256), 0, stream>>>(S, Sbf, W, Wk2, zbf);
  k_cvt_x<<<dim3(4096), dim3(256), 0, stream>>>(X, Xbf);
  k_proj<<<dim3(1024), dim3(256), 0, stream>>>(Wk2, Xbf, U3);

  hipError_t e0 = hipFuncSetAttribute((const void*)k_chain<false>,
                      hipFuncAttributeMaxDynamicSharedMemorySize, 131072);
  hipError_t e1 = hipFuncSetAttribute((const void*)k_chain<true>,
                      hipFuncAttributeMaxDynamicSharedMemorySize, 131072);
  (void)e0; (void)e1;

  // H2 = S*U3[t-1] + X*W2^T
  k_chain<false><<<dim3(256), dim3(512), 131072, stream>>>(
      U3, Sbf, Wk2 + 2 * (FF * FF), Xbf, zbf, H2, nullptr, nullptr);
  // H1 = S*H2[t-1] + X*W1^T
  k_chain<false><<<dim3(256), dim3(512), 131072, stream>>>(
      H2, Sbf, Wk2 + 1 * (FF * FF), Xbf, zbf, H1, nullptr, nullptr);
  // Y = S*H1[t-1] + X*W0^T + b
  k_chain<true><<<dim3(256), dim3(512), 131072, stream>>>(
      H1, Sbf, Wk2, Xbf, zbf, nullptr, Y, bvec);
}